// Round 3
// baseline (103.151 us; speedup 1.0000x reference)
//
#include <hip/hip_runtime.h>

static constexpr int TI = 128;   // i-rows per block
static constexpr int NTHREADS = 256;

// d_ws layout: [0..3] unsigned counter (memset to 0 each call)
//              [16 ..] float s_part[nb], c_part[nb], h_part[nb]

__global__ __launch_bounds__(NTHREADS) void egl_fused_kernel(
    const float* __restrict__ pred, const float* __restrict__ targ, int n, int nT,
    unsigned int* __restrict__ counter,
    float* __restrict__ ws_s, float* __restrict__ ws_c, float* __restrict__ ws_h,
    float* __restrict__ out) {
  const int nb = gridDim.x;

  // Decode blockIdx.x -> upper-triangular tile pair (ti <= tj).
  int bidx = blockIdx.x;
  int ti = 0, rem = bidx;
  while (rem >= nT - ti) { rem -= (nT - ti); ++ti; }
  const int tj = ti + rem;

  __shared__ alignas(16) float2 sj[TI];   // (p_j, t_j) for the j-tile
  const int tid  = threadIdx.x;
  const int il   = tid & (TI - 1);        // i-lane within tile
  const int half = tid >> 7;              // which 64-wide j-half this thread owns
  const int j0 = tj * TI;
  if (tid < TI) {
    int j = j0 + tid;
    float pj = (j < n) ? pred[j] : 0.0f;
    float tv = (j < n) ? targ[j] : 0.0f;
    sj[tid] = make_float2(pj, tv);
  }
  __syncthreads();

  const int i = ti * TI + il;
  const bool ivalid = (i < n);
  const float pi  = ivalid ? pred[i] : 0.0f;
  const float tiv = ivalid ? targ[i] : 0.0f;

  float s0 = 0.f, s1 = 0.f, s2 = 0.f, s3 = 0.f;
  float c0 = 0.f, c1 = 0.f, c2 = 0.f, c3 = 0.f;
  float hub = 0.f;

  const int jcount = min(TI, n - j0);

  // per-pair: sgn = clamp(t_i - t_j, -1, 1) in {-1,0,+1} (targets integer);
  // hinge = max(0, |sgn| - sgn*(p_i - p_j)); equal targets contribute 0 to both.
  if (ti != tj) {
    if (ivalid && jcount == TI) {
      const float4* sj4 = (const float4*)sj;   // 2 j's per 16B LDS broadcast read
      const int k0 = half * 32;
#pragma unroll
      for (int k = k0; k < k0 + 32; k += 2) {
        float4 a = sj4[k];
        float4 bq = sj4[k + 1];
        { float sg = fminf(fmaxf(tiv - a.y, -1.f), 1.f);
          s0 += fmaxf(fmaf(-sg, pi - a.x, fabsf(sg)), 0.f); c0 += fabsf(sg); }
        { float sg = fminf(fmaxf(tiv - a.w, -1.f), 1.f);
          s1 += fmaxf(fmaf(-sg, pi - a.z, fabsf(sg)), 0.f); c1 += fabsf(sg); }
        { float sg = fminf(fmaxf(tiv - bq.y, -1.f), 1.f);
          s2 += fmaxf(fmaf(-sg, pi - bq.x, fabsf(sg)), 0.f); c2 += fabsf(sg); }
        { float sg = fminf(fmaxf(tiv - bq.w, -1.f), 1.f);
          s3 += fmaxf(fmaf(-sg, pi - bq.z, fabsf(sg)), 0.f); c3 += fabsf(sg); }
      }
    } else if (ivalid) {
      const int jlo = half * 64;
      const int jhi = min(jlo + 64, jcount);
      for (int jj = jlo; jj < jhi; ++jj) {
        float2 a = sj[jj];
        float sg = fminf(fmaxf(tiv - a.y, -1.f), 1.f);
        s0 += fmaxf(fmaf(-sg, pi - a.x, fabsf(sg)), 0.f);
        c0 += fabsf(sg);
      }
    }
  } else {
    if (ivalid) {
      if (half == 0) {   // Huber once per i
        float d = pi - tiv;
        float ad = fabsf(d);
        hub = (ad < 1.0f) ? 0.5f * d * d : (ad - 0.5f);
      }
      const int jlo = max(il + 1, half * 64);
      const int jhi = min(half * 64 + 64, jcount);
      for (int jj = jlo; jj < jhi; ++jj) {
        float2 a = sj[jj];
        float sg = fminf(fmaxf(tiv - a.y, -1.f), 1.f);
        s0 += fmaxf(fmaf(-sg, pi - a.x, fabsf(sg)), 0.f);
        c0 += fabsf(sg);
      }
    }
  }

  float s = (s0 + s1) + (s2 + s3);
  float c = (c0 + c1) + (c2 + c3);

  // 64-lane wave reduction, then cross-wave via LDS
  for (int off = 32; off > 0; off >>= 1) {
    s   += __shfl_down(s, off, 64);
    c   += __shfl_down(c, off, 64);
    hub += __shfl_down(hub, off, 64);
  }
  __shared__ float red[4][3];
  __shared__ bool is_last;
  if ((tid & 63) == 0) {
    int w = tid >> 6;
    red[w][0] = s; red[w][1] = c; red[w][2] = hub;
  }
  __syncthreads();
  if (tid == 0) {
    ws_s[bidx] = (red[0][0] + red[1][0]) + (red[2][0] + red[3][0]);
    ws_c[bidx] = (red[0][1] + red[1][1]) + (red[2][1] + red[3][1]);
    ws_h[bidx] = (red[0][2] + red[1][2]) + (red[2][2] + red[3][2]);
    __threadfence();   // release partials to device scope
    unsigned int v = atomicAdd(counter, 1u);
    is_last = (v == (unsigned int)(nb - 1));
  }
  __syncthreads();
  if (!is_last) return;

  // ---- last block: finalize ----
  __threadfence();     // acquire: invalidate L1 so partials from other XCDs are fresh
  double ds = 0.0, dc = 0.0, dh = 0.0;
  for (int idx = tid; idx < nb; idx += NTHREADS) {
    ds += (double)ws_s[idx];
    dc += (double)ws_c[idx];
    dh += (double)ws_h[idx];
  }
  for (int off = 32; off > 0; off >>= 1) {
    ds += __shfl_down(ds, off, 64);
    dc += __shfl_down(dc, off, 64);
    dh += __shfl_down(dh, off, 64);
  }
  __shared__ double dred[4][3];
  if ((tid & 63) == 0) {
    int w = tid >> 6;
    dred[w][0] = ds; dred[w][1] = dc; dred[w][2] = dh;
  }
  __syncthreads();
  if (tid == 0) {
    double S = 0.0, C = 0.0, H = 0.0;
    for (int k = 0; k < 4; ++k) { S += dred[k][0]; C += dred[k][1]; H += dred[k][2]; }
    double huber = H / (double)n;
    double rank = (C > 0.0) ? (S / fmax(C, 1.0)) : 0.0;
    out[0] = (float)(0.7 * huber + 0.3 * rank);
  }
}

extern "C" void kernel_launch(void* const* d_in, const int* in_sizes, int n_in,
                              void* d_out, int out_size, void* d_ws, size_t ws_size,
                              hipStream_t stream) {
  const float* pred = (const float*)d_in[0];
  const float* targ = (const float*)d_in[1];
  const int n = in_sizes[0];

  const int nT = (n + TI - 1) / TI;
  const int nb = nT * (nT + 1) / 2;

  unsigned int* counter = (unsigned int*)d_ws;
  float* ws_s = (float*)((char*)d_ws + 16);
  float* ws_c = ws_s + nb;
  float* ws_h = ws_c + nb;

  hipMemsetAsync(d_ws, 0, 4, stream);   // zero the completion counter only
  egl_fused_kernel<<<nb, NTHREADS, 0, stream>>>(pred, targ, n, nT, counter,
                                                ws_s, ws_c, ws_h, (float*)d_out);
}

// Round 5
// 67.032 us; speedup vs baseline: 1.5388x; 1.5388x over previous
//
#include <hip/hip_runtime.h>

static constexpr int TI = 128;        // i-rows and j-cols per tile
static constexpr int NTHREADS = 256;  // 128 i-lanes x 2 j-halves

// d_ws layout: float s_part[nb], c_part[nb], h_part[nb].
// Every slot is written unconditionally by its block each call -> no memset.

// One tile-pair worth of accumulation. half selects which 64 j's this thread owns.
template <bool DIAG>
__device__ __forceinline__ void accum_tile(const float4* __restrict__ sj4,
                                           float pi, float tiv, int il, int half,
                                           float& s0, float& s1, float& s2, float& s3,
                                           float& c0, float& c1, float& c2, float& c3) {
  const int k0 = half * 32;  // float4 index base (each float4 = 2 j's)
#pragma unroll
  for (int k = 0; k < 32; k += 2) {
    float4 a = sj4[k0 + k];
    float4 b = sj4[k0 + k + 1];
    const int jb = 2 * (k0 + k);  // j-index of a.x/a.y pair
    {
      float sg = fminf(fmaxf(tiv - a.y, -1.f), 1.f);
      if (DIAG) sg = (jb + 0 > il) ? sg : 0.f;
      s0 += fmaxf(fmaf(-sg, pi - a.x, fabsf(sg)), 0.f); c0 += fabsf(sg);
    }
    {
      float sg = fminf(fmaxf(tiv - a.w, -1.f), 1.f);
      if (DIAG) sg = (jb + 1 > il) ? sg : 0.f;
      s1 += fmaxf(fmaf(-sg, pi - a.z, fabsf(sg)), 0.f); c1 += fabsf(sg);
    }
    {
      float sg = fminf(fmaxf(tiv - b.y, -1.f), 1.f);
      if (DIAG) sg = (jb + 2 > il) ? sg : 0.f;
      s2 += fmaxf(fmaf(-sg, pi - b.x, fabsf(sg)), 0.f); c2 += fabsf(sg);
    }
    {
      float sg = fminf(fmaxf(tiv - b.w, -1.f), 1.f);
      if (DIAG) sg = (jb + 3 > il) ? sg : 0.f;
      s3 += fmaxf(fmaf(-sg, pi - b.z, fabsf(sg)), 0.f); c3 += fabsf(sg);
    }
  }
}

__global__ __launch_bounds__(NTHREADS) void egl_pair_kernel(
    const float* __restrict__ pred, const float* __restrict__ targ, int n, int nT,
    float* __restrict__ ws_s, float* __restrict__ ws_c, float* __restrict__ ws_h) {
  // Decode blockIdx.x -> upper-triangular tile pair (ti <= tj).
  int bidx = blockIdx.x;
  int ti = 0, rem = bidx;
  while (rem >= nT - ti) { rem -= (nT - ti); ++ti; }
  const int tj = ti + rem;

  __shared__ alignas(16) float2 sj[TI];  // (p_j, t_j)
  const int tid  = threadIdx.x;
  const int il   = tid & (TI - 1);
  const int half = tid >> 7;
  const int j0 = tj * TI;
  if (tid < TI) {
    int j = j0 + tid;
    float pj = (j < n) ? pred[j] : 0.0f;
    float tv = (j < n) ? targ[j] : 0.0f;
    sj[tid] = make_float2(pj, tv);
  }
  __syncthreads();

  const int i = ti * TI + il;
  const bool ivalid = (i < n);
  const float pi  = ivalid ? pred[i] : 0.0f;
  const float tiv = ivalid ? targ[i] : 0.0f;

  float s0 = 0.f, s1 = 0.f, s2 = 0.f, s3 = 0.f;
  float c0 = 0.f, c1 = 0.f, c2 = 0.f, c3 = 0.f;
  float hub = 0.f;

  const int jcount = min(TI, n - j0);
  const float4* sj4 = (const float4*)sj;

  // per-pair: sg = clamp(t_i - t_j, -1, 1) in {-1,0,+1} (targets integer);
  // hinge = max(0, |sg| - sg*(p_i - p_j)); equal targets contribute 0 to both.
  if (ivalid) {
    if (ti != tj) {
      if (jcount == TI) {
        accum_tile<false>(sj4, pi, tiv, il, half, s0, s1, s2, s3, c0, c1, c2, c3);
      } else {
        const int jlo = half * 64;
        const int jhi = min(jlo + 64, jcount);
        for (int jj = jlo; jj < jhi; ++jj) {
          float2 a = sj[jj];
          float sg = fminf(fmaxf(tiv - a.y, -1.f), 1.f);
          s0 += fmaxf(fmaf(-sg, pi - a.x, fabsf(sg)), 0.f);
          c0 += fabsf(sg);
        }
      }
    } else {
      if (half == 0) {  // Huber once per element i
        float d = pi - tiv;
        float ad = fabsf(d);
        hub = (ad < 1.0f) ? 0.5f * d * d : (ad - 0.5f);
      }
      if (jcount == TI) {
        accum_tile<true>(sj4, pi, tiv, il, half, s0, s1, s2, s3, c0, c1, c2, c3);
      } else {
        const int jlo = max(il + 1, half * 64);
        const int jhi = min(half * 64 + 64, jcount);
        for (int jj = jlo; jj < jhi; ++jj) {
          float2 a = sj[jj];
          float sg = fminf(fmaxf(tiv - a.y, -1.f), 1.f);
          s0 += fmaxf(fmaf(-sg, pi - a.x, fabsf(sg)), 0.f);
          c0 += fabsf(sg);
        }
      }
    }
  }

  float s = (s0 + s1) + (s2 + s3);
  float c = (c0 + c1) + (c2 + c3);

  for (int off = 32; off > 0; off >>= 1) {
    s   += __shfl_down(s, off, 64);
    c   += __shfl_down(c, off, 64);
    hub += __shfl_down(hub, off, 64);
  }
  __shared__ float red[4][3];
  if ((tid & 63) == 0) {
    int w = tid >> 6;
    red[w][0] = s; red[w][1] = c; red[w][2] = hub;
  }
  __syncthreads();
  if (tid == 0) {
    ws_s[bidx] = (red[0][0] + red[1][0]) + (red[2][0] + red[3][0]);
    ws_c[bidx] = (red[0][1] + red[1][1]) + (red[2][1] + red[3][1]);
    ws_h[bidx] = (red[0][2] + red[1][2]) + (red[2][2] + red[3][2]);
  }
}

__global__ __launch_bounds__(256) void egl_finalize(
    const float* __restrict__ ws_s, const float* __restrict__ ws_c,
    const float* __restrict__ ws_h, int nb, int n, float* __restrict__ out) {
  double s = 0.0, c = 0.0, h = 0.0;
  for (int idx = threadIdx.x; idx < nb; idx += 256) {
    s += (double)ws_s[idx];
    c += (double)ws_c[idx];
    h += (double)ws_h[idx];
  }
  for (int off = 32; off > 0; off >>= 1) {
    s += __shfl_down(s, off, 64);
    c += __shfl_down(c, off, 64);
    h += __shfl_down(h, off, 64);
  }
  __shared__ double red[4][3];
  int w = threadIdx.x >> 6;
  if ((threadIdx.x & 63) == 0) { red[w][0] = s; red[w][1] = c; red[w][2] = h; }
  __syncthreads();
  if (threadIdx.x == 0) {
    double S = 0.0, C = 0.0, H = 0.0;
    for (int k = 0; k < 4; ++k) { S += red[k][0]; C += red[k][1]; H += red[k][2]; }
    double huber = H / (double)n;
    double rank = (C > 0.0) ? (S / fmax(C, 1.0)) : 0.0;
    out[0] = (float)(0.7 * huber + 0.3 * rank);
  }
}

extern "C" void kernel_launch(void* const* d_in, const int* in_sizes, int n_in,
                              void* d_out, int out_size, void* d_ws, size_t ws_size,
                              hipStream_t stream) {
  const float* pred = (const float*)d_in[0];
  const float* targ = (const float*)d_in[1];
  const int n = in_sizes[0];

  const int nT = (n + TI - 1) / TI;
  const int nb = nT * (nT + 1) / 2;

  float* ws_s = (float*)d_ws;
  float* ws_c = ws_s + nb;
  float* ws_h = ws_c + nb;

  egl_pair_kernel<<<nb, NTHREADS, 0, stream>>>(pred, targ, n, nT, ws_s, ws_c, ws_h);
  egl_finalize<<<1, 256, 0, stream>>>(ws_s, ws_c, ws_h, nb, n, (float*)d_out);
}